// Round 7
// baseline (202.862 us; speedup 1.0000x reference)
//
#include <hip/hip_runtime.h>
#include <cstdint>
#include <cmath>

// RandomPhongShader: exact reproduction of JAX threefry-partitionable RNG +
// XLA CPU float32 numerics, fused shader.
//
// Round 7: round-6 logic (integer heaviside thresholds, slim argmax score
// chain, margin-at-end fallback) with round-5 register discipline:
// phase-local loads, p2f reduced to an 8-bit mask on load, colors loaded
// only in the epilogue. Target VGPR <= 64 for 8 waves/SIMD.
// NO waves/EU cap (round-2 spill lesson); no LDS.
//
// Shapes: N=8,H=256,W=256,K=8, NB_SAMPLES=4. Pixels P = N*H*W = 524288.
// partitionable bits(i) = o0 ^ o1 of threefry2x32(key, (0, i))
// split(key(1)): kh = cipher((0,1),(0,0)), ka = cipher((0,1),(0,1))

#pragma clang fp contract(off)

#define NPIX 524288
#define STRIDE_H 4194304u
#define STRIDE_A 4718592u
#define BAND_A 5e-5f

__device__ __forceinline__ uint32_t rotl32(uint32_t v, int n) {
  return (v << n) | (v >> (32 - n));   // v_alignbit_b32
}

__device__ __forceinline__ void tf2x32(uint32_t k0, uint32_t k1,
                                       uint32_t c0, uint32_t c1,
                                       uint32_t& o0, uint32_t& o1) {
  const uint32_t k2 = k0 ^ k1 ^ 0x1BD11BDAu;
  uint32_t x0 = c0 + k0, x1 = c1 + k1;
#define TFR(r) { x0 += x1; x1 = rotl32(x1, r); x1 ^= x0; }
  TFR(13) TFR(15) TFR(26) TFR(6)
  x0 += k1;  x1 += k2 + 1u;
  TFR(17) TFR(29) TFR(16) TFR(24)
  x0 += k2;  x1 += k0 + 2u;
  TFR(13) TFR(15) TFR(26) TFR(6)
  x0 += k0;  x1 += k1 + 3u;
  TFR(17) TFR(29) TFR(16) TFR(24)
  x0 += k1;  x1 += k2 + 4u;
  TFR(13) TFR(15) TFR(26) TFR(6)
  x0 += k2;  x1 += k0 + 5u;
#undef TFR
  o0 = x0; o1 = x1;
}

// ---- exact path (cold): rounds-3..6-validated numerics ----
__device__ __forceinline__ double fast_log(double z) {
  uint64_t b = __double_as_longlong(z);
  int E = (int)(b >> 52) - 1023;
  double m = __longlong_as_double((b & 0x000FFFFFFFFFFFFFULL) |
                                  0x3FF0000000000000ULL);  // [1,2)
  bool c = m > 1.4142135623730951;
  m = c ? m * 0.5 : m;   // exact
  E = c ? E + 1 : E;
  double d = m + 1.0;
  double r = __builtin_amdgcn_rcp(d);
  r = fma(r, fma(-d, r, 1.0), r);
  r = fma(r, fma(-d, r, 1.0), r);              // ~2e-16 rel
  double s = (m - 1.0) * r;
  double u = s * s;
  double p = 1.0 / 19.0;
  p = fma(p, u, 1.0 / 17.0);
  p = fma(p, u, 1.0 / 15.0);
  p = fma(p, u, 1.0 / 13.0);
  p = fma(p, u, 1.0 / 11.0);
  p = fma(p, u, 1.0 / 9.0);
  p = fma(p, u, 1.0 / 7.0);
  p = fma(p, u, 1.0 / 5.0);
  p = fma(p, u, 1.0 / 3.0);
  p = fma(p, u, 1.0);
  double lm = (2.0 * s) * p;
  const double LN2_HI = 6.93147180369123816490e-01;
  const double LN2_LO = 1.90821492927058770002e-10;
  double e = (double)E;
  return fma(e, LN2_HI, fma(e, LN2_LO, lm));
}

__device__ __forceinline__ float normal_exact(uint32_t bits) {
  float f = __uint_as_float((bits >> 9) | 0x3f800000u) - 1.0f;  // exact
  const float lo = __uint_as_float(0xBF7FFFFFu);
  float v = __fadd_rn(__fmul_rn(f, 2.0f), lo);
  v = fmaxf(lo, v);
  float t = -__fmul_rn(v, v);
  float taylor = __fmul_rn(__fadd_rn(__fmul_rn(-0.5f, t), 1.0f), t);
  float lg = (float)fast_log((double)__fadd_rn(t, 1.0f));
  float l1p = (fabsf(t) < 1e-4f) ? taylor : lg;
  float w = -l1p;
  const bool lt = w < 5.0f;
  float ww = lt ? __fsub_rn(w, 2.5f) : __fsub_rn(__fsqrt_rn(w), 3.0f);
  float p  = lt ? 2.81022636e-08f : -0.000200214257f;
  p = __fadd_rn(lt ?  3.43273939e-07f :  0.000100950558f, __fmul_rn(p, ww));
  p = __fadd_rn(lt ? -3.5233877e-06f  :  0.00134934322f,  __fmul_rn(p, ww));
  p = __fadd_rn(lt ? -4.39150654e-06f : -0.00367342844f,  __fmul_rn(p, ww));
  p = __fadd_rn(lt ?  0.00021858087f  :  0.00573950773f,  __fmul_rn(p, ww));
  p = __fadd_rn(lt ? -0.00125372503f  : -0.0076224613f,   __fmul_rn(p, ww));
  p = __fadd_rn(lt ? -0.00417768164f  :  0.00943887047f,  __fmul_rn(p, ww));
  p = __fadd_rn(lt ?  0.246640727f    :  1.00167406f,     __fmul_rn(p, ww));
  p = __fadd_rn(lt ?  1.50140941f     :  2.83297682f,     __fmul_rn(p, ww));
  return __fmul_rn(__uint_as_float(0x3FB504F3u), __fmul_rn(p, v));
}

// ---- approx argmax score (hot). v kept bit-exact; log/poly approximated;
// |score_fast - score_exact| <~ 4e-6; margin BAND_A = 5e-5 -> >=12x safety.
__device__ __forceinline__ float score_fast(uint32_t bits, float zmj) {
  float f = __uint_as_float((bits >> 9) | 0x3f800000u) - 1.0f;  // exact
  const float lo = __uint_as_float(0xBF7FFFFFu);
  float v = fmaxf(lo, __fmaf_rn(f, 2.0f, lo));
  float t = -__fmul_rn(v, v);
  float u = __fadd_rn(t, 1.0f);
  float L = __builtin_amdgcn_logf(u);            // log2(u), <=0
  float ww = __fmaf_rn(-0.69314718f, L, -2.5f);  // w - 2.5
  float p = 2.81022636e-08f;
  p = __fmaf_rn(p, ww,  3.43273939e-07f);
  p = __fmaf_rn(p, ww, -3.5233877e-06f);
  p = __fmaf_rn(p, ww, -4.39150654e-06f);
  p = __fmaf_rn(p, ww,  0.00021858087f);
  p = __fmaf_rn(p, ww, -0.00125372503f);
  p = __fmaf_rn(p, ww, -0.00417768164f);
  p = __fmaf_rn(p, ww,  0.246640727f);
  p = __fmaf_rn(p, ww,  1.50140941f);
  if (__builtin_expect(__ballot(L <= -7.2134752f) != 0ull, 0)) {  // w>=5
    float w = __fmul_rn(-0.69314718f, L);
    float w2 = __builtin_amdgcn_sqrtf(w) - 3.0f;
    float q = -0.000200214257f;
    q = __fmaf_rn(q, w2,  0.000100950558f);
    q = __fmaf_rn(q, w2,  0.00134934322f);
    q = __fmaf_rn(q, w2, -0.00367342844f);
    q = __fmaf_rn(q, w2,  0.00573950773f);
    q = __fmaf_rn(q, w2, -0.0076224613f);
    q = __fmaf_rn(q, w2,  0.00943887047f);
    q = __fmaf_rn(q, w2,  1.00167406f);
    q = __fmaf_rn(q, w2,  2.83297682f);
    p = (L <= -7.2134752f) ? q : p;
  }
  return __fmaf_rn(__fmul_rn(p, v), 0.14142136f, zmj);  // zm + 0.1*sqrt2*p*v
}

__global__ __launch_bounds__(256) void RandomPhongShader_kernel(
    const float* __restrict__ colors,   // (P,8,3)
    const float* __restrict__ dists,    // (P,8)
    const float* __restrict__ zbuf,     // (P,8)
    const int*   __restrict__ p2f,      // (P,8)
    const float* __restrict__ bg,       // (3,)
    float* __restrict__ out)            // (P,4)
{
  const int P = blockIdx.x * 256 + threadIdx.x;  // grid exact: 2048*256

  uint32_t kh0, kh1, ka0, ka1;                   // constant-folded
  tf2x32(0u, 1u, 0u, 0u, kh0, kh1);
  tf2x32(0u, 1u, 0u, 1u, ka0, ka1);

  // ---- phase 0: integer thresholds (dists live only here).
  // decision (bits>>9) >= T, T = ceil((erf(10*d/sqrt2)+0.99999994)*2^22);
  // band +-6 units covers erf err + RN wiggle + conversion (round-6 valid).
  int Tm6[8];
  {
    const float4* d4 = reinterpret_cast<const float4*>(dists + (size_t)P * 8);
    float4 a = d4[0], b = d4[1];
    float dk[8] = {a.x,a.y,a.z,a.w,b.x,b.y,b.z,b.w};
    #pragma unroll
    for (int k = 0; k < 8; ++k) {
      float y = fabsf(dk[k]) * 7.0710678f;
      float tt = __builtin_amdgcn_rcpf(__fmaf_rn(0.3275911f, y, 1.0f));
      float ex = __builtin_amdgcn_exp2f(__fmul_rn(-1.4426951f, y * y));
      float pp = 1.061405429f;
      pp = __fmaf_rn(pp, tt, -1.453152027f);
      pp = __fmaf_rn(pp, tt,  1.421413741f);
      pp = __fmaf_rn(pp, tt, -0.284496736f);
      pp = __fmaf_rn(pp, tt,  0.254829592f);
      float er = __fmaf_rn(-pp * tt, ex, 1.0f);
      float vs = copysignf(er, dk[k]);
      int T = (int)ceilf(__fmul_rn(__fadd_rn(vs, 0.99999994f), 4194304.0f));
      Tm6[k] = T - 6;
    }
  }

  // ---- phase 1: heaviside counts (integer hot path; Tm6+cntP live) ----
  uint32_t cntP = 0;          // 8 nibbles
  bool redoH = false;
  {
    uint32_t cH = (uint32_t)P * 8u;
    #pragma unroll 1
    for (int s = 0; s < 4; ++s) {
      #pragma unroll
      for (int k = 0; k < 8; ++k) {
        uint32_t o0, o1;
        tf2x32(kh0, kh1, 0u, cH + (uint32_t)k, o0, o1);
        int m = (int)((o0 ^ o1) >> 9);
        int sub = m - Tm6[k];
        cntP += (sub >= 6) ? (1u << (4 * k)) : 0u;
        redoH |= ((uint32_t)sub <= 12u);
      }
      cH += STRIDE_H;
    }
  }
  if (__builtin_expect(__ballot(redoH) != 0ull, 0)) {
    if (redoH) {   // exec-masked: redo all 32 draws exactly (cold reloads)
      uint32_t c2 = 0;
      uint32_t cH = (uint32_t)P * 8u;
      #pragma unroll 1
      for (int s = 0; s < 4; ++s) {
        #pragma unroll 1
        for (int k = 0; k < 8; ++k) {
          uint32_t o0, o1;
          tf2x32(kh0, kh1, 0u, cH + (uint32_t)k, o0, o1);
          float nz = normal_exact(o0 ^ o1);
          float x = -dists[(size_t)P * 8 + k];
          c2 += (__fadd_rn(x, __fmul_rn(0.1f, nz)) >= 0.0f) ? (1u << (4 * k)) : 0u;
        }
        cH += STRIDE_H;
      }
      cntP = c2;
    }
  }
  // Tm6 dead here.

  // ---- phase 2: mask (1 reg), z_inv, z_map, alpha ----
  uint32_t msk;   // bit k = (p2f[k] >= 0)
  {
    const int4* m4 = reinterpret_cast<const int4*>(p2f + (size_t)P * 8);
    int4 f = m4[0], g = m4[1];
    msk  = (f.x >= 0 ? 1u : 0u) | (f.y >= 0 ? 2u : 0u)
         | (f.z >= 0 ? 4u : 0u) | (f.w >= 0 ? 8u : 0u)
         | (g.x >= 0 ? 16u : 0u) | (g.y >= 0 ? 32u : 0u)
         | (g.z >= 0 ? 64u : 0u) | (g.w >= 0 ? 128u : 0u);
  }
  float zinv[8], zmax;
  {
    const double D99 = 1.0 / 99.0;   // f64 recip-mul == fdiv to <=1ulp (r6-ok)
    const float4* z4 = reinterpret_cast<const float4*>(zbuf + (size_t)P * 8);
    float4 c = z4[0], e = z4[1];
    float zk[8] = {c.x,c.y,c.z,c.w,e.x,e.y,e.z,e.w};
    #pragma unroll
    for (int k = 0; k < 8; ++k) {
      const float m = ((msk >> k) & 1u) ? 1.0f : 0.0f;
      float a = __fsub_rn(100.0f, zk[k]);
      float zi = __fmul_rn((float)((double)a * D99), m);
      zinv[k] = zi;
      zmax = (k == 0) ? zi : fmaxf(zmax, zi);
    }
  }
  zmax = fmaxf(zmax, 1e-10f);

  const float lg0 = (float)-23.025850916589025;  // log(1e-10f)
  const float lg1 = (float)-1.3862943611198906;  // log(0.25)
  const float lg2 = (float)-0.6931471805599453;  // log(0.5)
  const float lg3 = (float)-0.2876820724517809;  // log(0.75)
  const double D01 = 1.0 / (double)0.1f;

  float alpha = 1.0f;
  float zm[9];
  #pragma unroll
  for (int k = 0; k < 8; ++k) {
    const int cntk = (int)((cntP >> (4 * k)) & 15u);
    const bool mb = ((msk >> k) & 1u) != 0u;
    const float pm = mb ? __fmul_rn((float)cntk, 0.25f) : 0.0f;
    alpha *= (1.0f - pm);  // exact
    const int i = mb ? cntk : 0;
    const float lg = (i == 0) ? lg0 : (i == 1) ? lg1 : (i == 2) ? lg2
                   : (i == 3) ? lg3 : 0.0f;
    float sdf = __fsub_rn(zinv[k], zmax);
    zm[k] = __fadd_rn(lg, (float)((double)sdf * D01));
  }
  zm[8] = (float)((double)__fsub_rn(1e-10f, zmax) * D01);
  // zinv, msk, cntP dead here; live: zm[9], alpha.

  // ---- phase 3: random_argmax (approx scan + margin-at-end fallback) ----
  uint32_t amPack = 0;
  uint32_t cA = (uint32_t)P * 9u;
  #pragma unroll 1
  for (int s = 0; s < 4; ++s) {
    int am = 0;
    float best = -3.4e38f, second = -3.4e38f;
    #pragma unroll
    for (int j = 0; j < 9; ++j) {
      uint32_t o0, o1;
      tf2x32(ka0, ka1, 0u, cA + (uint32_t)j, o0, o1);
      float vv = score_fast(o0 ^ o1, zm[j]);
      bool g = vv > best;
      second = g ? best : fmaxf(second, vv);
      best = g ? vv : best;
      am = g ? j : am;
    }
    bool fl = __fsub_rn(best, second) < BAND_A;
    if (__builtin_expect(__ballot(fl) != 0ull, 0)) {
      if (fl) {   // exec-masked exact redo of this sample
        int ame = 0;
        float be = -3.4e38f;
        #pragma unroll
        for (int j = 0; j < 9; ++j) {
          uint32_t o0, o1;
          tf2x32(ka0, ka1, 0u, cA + (uint32_t)j, o0, o1);
          float nz = normal_exact(o0 ^ o1);
          float ve = __fadd_rn(zm[j], __fmul_rn(0.1f, nz));
          bool g = ve > be;
          be = g ? ve : be;
          ame = g ? j : ame;
        }
        am = ame;
      }
    }
    amPack += 1u << (3 * am);
    cA += STRIDE_A;
  }
  // zm dead here; live: amPack, alpha.

  // ---- phase 4: epilogue (colors live only here) ----
  float rgb[3] = {0.0f, 0.0f, 0.0f};
  {
    const float4* c4 = reinterpret_cast<const float4*>(colors + (size_t)P * 24);
    float cc[24];
    #pragma unroll
    for (int q = 0; q < 6; ++q) {
      float4 t = c4[q];
      cc[q*4+0]=t.x; cc[q*4+1]=t.y; cc[q*4+2]=t.z; cc[q*4+3]=t.w;
    }
    #pragma unroll
    for (int c = 0; c < 3; ++c) {
      float acc = 0.0f;
      #pragma unroll
      for (int k = 0; k < 8; ++k) {
        float wk = __fmul_rn(0.25f, (float)((amPack >> (3 * k)) & 7u));
        acc = __fadd_rn(acc, __fmul_rn(wk, cc[k * 3 + c]));
      }
      float wb = __fmul_rn(0.25f, (float)((amPack >> 24) & 7u));
      rgb[c] = __fadd_rn(acc, __fmul_rn(wb, bg[c]));
    }
  }

  float4 o;
  o.x = rgb[0]; o.y = rgb[1]; o.z = rgb[2];
  o.w = __fsub_rn(1.0f, alpha);
  reinterpret_cast<float4*>(out)[P] = o;
}

extern "C" void kernel_launch(void* const* d_in, const int* in_sizes, int n_in,
                              void* d_out, int out_size, void* d_ws, size_t ws_size,
                              hipStream_t stream) {
  const float* colors = (const float*)d_in[0];
  const float* dists  = (const float*)d_in[1];
  const float* zbuf   = (const float*)d_in[2];
  const int*   p2f    = (const int*)d_in[3];
  const float* bg     = (const float*)d_in[4];
  float* out = (float*)d_out;
  dim3 grid(NPIX / 256), block(256);
  hipLaunchKernelGGL(RandomPhongShader_kernel, grid, block, 0, stream,
                     colors, dists, zbuf, p2f, bg, out);
}

// Round 8
// 190.915 us; speedup vs baseline: 1.0626x; 1.0626x over previous
//
#include <hip/hip_runtime.h>
#include <cstdint>
#include <cmath>

// RandomPhongShader: exact reproduction of JAX threefry-partitionable RNG +
// XLA CPU float32 numerics, fused shader.
//
// Round 8: round-5 register shape + round-6 hot logic.
//  - Integer heaviside compares (T from A&S erf, band +-6 units), margin-at-
//    end argmax fallback (both validated rounds 6-7).
//  - ALL cold fallback loops rolled (#pragma unroll 1) with zm staged in LDS
//    for dynamic indexing -- in round 5 this kept VGPR at 36 / occ 41%; the
//    round-6/7 unrolled cold blocks drove VGPR to 72-76 / occ 25%.
//  - Phase-2 divisions back to __fdiv_rn (f64 recip-mul pairs cost VGPRs,
//    saved nothing in issued work: r5 90.6 vs r6 94.3 us-eq).
//  - NO waves/EU cap (round-2 spill catastrophe).
//
// Shapes: N=8,H=256,W=256,K=8, NB_SAMPLES=4. Pixels P = N*H*W = 524288.
// partitionable bits(i) = o0 ^ o1 of threefry2x32(key, (0, i))
// split(key(1)): kh = cipher((0,1),(0,0)), ka = cipher((0,1),(0,1))

#pragma clang fp contract(off)

#define NPIX 524288
#define STRIDE_H 4194304u
#define STRIDE_A 4718592u
#define BAND_A 5e-5f

__device__ __forceinline__ uint32_t rotl32(uint32_t v, int n) {
  return (v << n) | (v >> (32 - n));   // v_alignbit_b32
}

__device__ __forceinline__ void tf2x32(uint32_t k0, uint32_t k1,
                                       uint32_t c0, uint32_t c1,
                                       uint32_t& o0, uint32_t& o1) {
  const uint32_t k2 = k0 ^ k1 ^ 0x1BD11BDAu;
  uint32_t x0 = c0 + k0, x1 = c1 + k1;
#define TFR(r) { x0 += x1; x1 = rotl32(x1, r); x1 ^= x0; }
  TFR(13) TFR(15) TFR(26) TFR(6)
  x0 += k1;  x1 += k2 + 1u;
  TFR(17) TFR(29) TFR(16) TFR(24)
  x0 += k2;  x1 += k0 + 2u;
  TFR(13) TFR(15) TFR(26) TFR(6)
  x0 += k0;  x1 += k1 + 3u;
  TFR(17) TFR(29) TFR(16) TFR(24)
  x0 += k1;  x1 += k2 + 4u;
  TFR(13) TFR(15) TFR(26) TFR(6)
  x0 += k2;  x1 += k0 + 5u;
#undef TFR
  o0 = x0; o1 = x1;
}

// ---- exact path (cold): rounds-3..7-validated numerics ----
__device__ __forceinline__ double fast_log(double z) {
  uint64_t b = __double_as_longlong(z);
  int E = (int)(b >> 52) - 1023;
  double m = __longlong_as_double((b & 0x000FFFFFFFFFFFFFULL) |
                                  0x3FF0000000000000ULL);  // [1,2)
  bool c = m > 1.4142135623730951;
  m = c ? m * 0.5 : m;   // exact
  E = c ? E + 1 : E;
  double d = m + 1.0;
  double r = __builtin_amdgcn_rcp(d);
  r = fma(r, fma(-d, r, 1.0), r);
  r = fma(r, fma(-d, r, 1.0), r);              // ~2e-16 rel
  double s = (m - 1.0) * r;
  double u = s * s;
  double p = 1.0 / 19.0;
  p = fma(p, u, 1.0 / 17.0);
  p = fma(p, u, 1.0 / 15.0);
  p = fma(p, u, 1.0 / 13.0);
  p = fma(p, u, 1.0 / 11.0);
  p = fma(p, u, 1.0 / 9.0);
  p = fma(p, u, 1.0 / 7.0);
  p = fma(p, u, 1.0 / 5.0);
  p = fma(p, u, 1.0 / 3.0);
  p = fma(p, u, 1.0);
  double lm = (2.0 * s) * p;
  const double LN2_HI = 6.93147180369123816490e-01;
  const double LN2_LO = 1.90821492927058770002e-10;
  double e = (double)E;
  return fma(e, LN2_HI, fma(e, LN2_LO, lm));
}

__device__ __forceinline__ float normal_exact(uint32_t bits) {
  float f = __uint_as_float((bits >> 9) | 0x3f800000u) - 1.0f;  // exact
  const float lo = __uint_as_float(0xBF7FFFFFu);
  float v = __fadd_rn(__fmul_rn(f, 2.0f), lo);
  v = fmaxf(lo, v);
  float t = -__fmul_rn(v, v);
  float taylor = __fmul_rn(__fadd_rn(__fmul_rn(-0.5f, t), 1.0f), t);
  float lg = (float)fast_log((double)__fadd_rn(t, 1.0f));
  float l1p = (fabsf(t) < 1e-4f) ? taylor : lg;
  float w = -l1p;
  const bool lt = w < 5.0f;
  float ww = lt ? __fsub_rn(w, 2.5f) : __fsub_rn(__fsqrt_rn(w), 3.0f);
  float p  = lt ? 2.81022636e-08f : -0.000200214257f;
  p = __fadd_rn(lt ?  3.43273939e-07f :  0.000100950558f, __fmul_rn(p, ww));
  p = __fadd_rn(lt ? -3.5233877e-06f  :  0.00134934322f,  __fmul_rn(p, ww));
  p = __fadd_rn(lt ? -4.39150654e-06f : -0.00367342844f,  __fmul_rn(p, ww));
  p = __fadd_rn(lt ?  0.00021858087f  :  0.00573950773f,  __fmul_rn(p, ww));
  p = __fadd_rn(lt ? -0.00125372503f  : -0.0076224613f,   __fmul_rn(p, ww));
  p = __fadd_rn(lt ? -0.00417768164f  :  0.00943887047f,  __fmul_rn(p, ww));
  p = __fadd_rn(lt ?  0.246640727f    :  1.00167406f,     __fmul_rn(p, ww));
  p = __fadd_rn(lt ?  1.50140941f     :  2.83297682f,     __fmul_rn(p, ww));
  return __fmul_rn(__uint_as_float(0x3FB504F3u), __fmul_rn(p, v));
}

// ---- approx argmax score (hot). v kept bit-exact; log/poly approximated;
// |score_fast - score_exact| <~ 4e-6; margin BAND_A = 5e-5 -> >=12x safety.
__device__ __forceinline__ float score_fast(uint32_t bits, float zmj) {
  float f = __uint_as_float((bits >> 9) | 0x3f800000u) - 1.0f;  // exact
  const float lo = __uint_as_float(0xBF7FFFFFu);
  float v = fmaxf(lo, __fmaf_rn(f, 2.0f, lo));
  float t = -__fmul_rn(v, v);
  float u = __fadd_rn(t, 1.0f);
  float L = __builtin_amdgcn_logf(u);            // log2(u), <=0
  float ww = __fmaf_rn(-0.69314718f, L, -2.5f);  // w - 2.5
  float p = 2.81022636e-08f;
  p = __fmaf_rn(p, ww,  3.43273939e-07f);
  p = __fmaf_rn(p, ww, -3.5233877e-06f);
  p = __fmaf_rn(p, ww, -4.39150654e-06f);
  p = __fmaf_rn(p, ww,  0.00021858087f);
  p = __fmaf_rn(p, ww, -0.00125372503f);
  p = __fmaf_rn(p, ww, -0.00417768164f);
  p = __fmaf_rn(p, ww,  0.246640727f);
  p = __fmaf_rn(p, ww,  1.50140941f);
  if (__builtin_expect(__ballot(L <= -7.2134752f) != 0ull, 0)) {  // w>=5
    float w = __fmul_rn(-0.69314718f, L);
    float w2 = __builtin_amdgcn_sqrtf(w) - 3.0f;
    float q = -0.000200214257f;
    q = __fmaf_rn(q, w2,  0.000100950558f);
    q = __fmaf_rn(q, w2,  0.00134934322f);
    q = __fmaf_rn(q, w2, -0.00367342844f);
    q = __fmaf_rn(q, w2,  0.00573950773f);
    q = __fmaf_rn(q, w2, -0.0076224613f);
    q = __fmaf_rn(q, w2,  0.00943887047f);
    q = __fmaf_rn(q, w2,  1.00167406f);
    q = __fmaf_rn(q, w2,  2.83297682f);
    p = (L <= -7.2134752f) ? q : p;
  }
  return __fmaf_rn(__fmul_rn(p, v), 0.14142136f, zmj);  // zm + 0.1*sqrt2*p*v
}

__global__ __launch_bounds__(256) void RandomPhongShader_kernel(
    const float* __restrict__ colors,   // (P,8,3)
    const float* __restrict__ dists,    // (P,8)
    const float* __restrict__ zbuf,     // (P,8)
    const int*   __restrict__ p2f,      // (P,8)
    const float* __restrict__ bg,       // (3,)
    float* __restrict__ out)            // (P,4)
{
  __shared__ float zmS[256][9];   // staged z_map for rolled cold loops
  const int tid = threadIdx.x;
  const int P = blockIdx.x * 256 + tid;   // grid exact: 2048*256

  uint32_t kh0, kh1, ka0, ka1;            // constant-folded
  tf2x32(0u, 1u, 0u, 0u, kh0, kh1);
  tf2x32(0u, 1u, 0u, 1u, ka0, ka1);

  // ---- phase 0: integer thresholds.
  // decision (bits>>9) >= T, T = ceil((erf(10*d/sqrt2)+0.99999994)*2^22);
  // band +-6 units covers erf err + RN wiggle + conversion (rounds 6-7 ok).
  int Tm6[8];
  {
    const float4* d4 = reinterpret_cast<const float4*>(dists + (size_t)P * 8);
    float4 a = d4[0], b = d4[1];
    float dk[8] = {a.x,a.y,a.z,a.w,b.x,b.y,b.z,b.w};
    #pragma unroll
    for (int k = 0; k < 8; ++k) {
      float y = fabsf(dk[k]) * 7.0710678f;
      float tt = __builtin_amdgcn_rcpf(__fmaf_rn(0.3275911f, y, 1.0f));
      float ex = __builtin_amdgcn_exp2f(__fmul_rn(-1.4426951f, y * y));
      float pp = 1.061405429f;
      pp = __fmaf_rn(pp, tt, -1.453152027f);
      pp = __fmaf_rn(pp, tt,  1.421413741f);
      pp = __fmaf_rn(pp, tt, -0.284496736f);
      pp = __fmaf_rn(pp, tt,  0.254829592f);
      float er = __fmaf_rn(-pp * tt, ex, 1.0f);
      float vs = copysignf(er, dk[k]);
      int T = (int)ceilf(__fmul_rn(__fadd_rn(vs, 0.99999994f), 4194304.0f));
      Tm6[k] = T - 6;
    }
  }

  // ---- phase 1: heaviside counts (integer hot path) ----
  uint32_t cntP = 0;          // 8 nibbles
  bool redoH = false;
  {
    uint32_t cH = (uint32_t)P * 8u;
    #pragma unroll 1
    for (int s = 0; s < 4; ++s) {
      #pragma unroll
      for (int k = 0; k < 8; ++k) {
        uint32_t o0, o1;
        tf2x32(kh0, kh1, 0u, cH + (uint32_t)k, o0, o1);
        int m = (int)((o0 ^ o1) >> 9);
        int sub = m - Tm6[k];
        cntP += (sub >= 6) ? (1u << (4 * k)) : 0u;
        redoH |= ((uint32_t)sub <= 12u);
      }
      cH += STRIDE_H;
    }
  }
  if (__builtin_expect(__ballot(redoH) != 0ull, 0)) {
    if (redoH) {   // exec-masked: redo all 32 draws exactly, fully rolled
      uint32_t c2 = 0;
      #pragma unroll 1
      for (int i = 0; i < 32; ++i) {   // i = s*8 + k
        uint32_t s = (uint32_t)i >> 3, k = (uint32_t)i & 7u;
        uint32_t o0, o1;
        tf2x32(kh0, kh1, 0u, s * STRIDE_H + (uint32_t)P * 8u + k, o0, o1);
        float nz = normal_exact(o0 ^ o1);
        float x = -dists[(size_t)P * 8 + k];   // cold reload
        c2 += (__fadd_rn(x, __fmul_rn(0.1f, nz)) >= 0.0f) ? (1u << (4 * k)) : 0u;
      }
      cntP = c2;
    }
  }
  // Tm6 dead here.

  // ---- phase 2: mask, z_inv, z_map (exact; __fdiv_rn as in rounds 1-5) ----
  uint32_t msk;   // bit k = (p2f[k] >= 0)
  {
    const int4* m4 = reinterpret_cast<const int4*>(p2f + (size_t)P * 8);
    int4 f = m4[0], g = m4[1];
    msk  = (f.x >= 0 ? 1u : 0u) | (f.y >= 0 ? 2u : 0u)
         | (f.z >= 0 ? 4u : 0u) | (f.w >= 0 ? 8u : 0u)
         | (g.x >= 0 ? 16u : 0u) | (g.y >= 0 ? 32u : 0u)
         | (g.z >= 0 ? 64u : 0u) | (g.w >= 0 ? 128u : 0u);
  }
  float zinv[8], zmax;
  {
    const float4* z4 = reinterpret_cast<const float4*>(zbuf + (size_t)P * 8);
    float4 c = z4[0], e = z4[1];
    float zk[8] = {c.x,c.y,c.z,c.w,e.x,e.y,e.z,e.w};
    #pragma unroll
    for (int k = 0; k < 8; ++k) {
      const float m = ((msk >> k) & 1u) ? 1.0f : 0.0f;
      float zi = __fmul_rn(__fdiv_rn(__fsub_rn(100.0f, zk[k]), 99.0f), m);
      zinv[k] = zi;
      zmax = (k == 0) ? zi : fmaxf(zmax, zi);
    }
  }
  zmax = fmaxf(zmax, 1e-10f);

  const float lg0 = (float)-23.025850916589025;  // log(1e-10f)
  const float lg1 = (float)-1.3862943611198906;  // log(0.25)
  const float lg2 = (float)-0.6931471805599453;  // log(0.5)
  const float lg3 = (float)-0.2876820724517809;  // log(0.75)

  float alpha = 1.0f;
  float zm[9];
  #pragma unroll
  for (int k = 0; k < 8; ++k) {
    const int cntk = (int)((cntP >> (4 * k)) & 15u);
    const bool mb = ((msk >> k) & 1u) != 0u;
    const float pm = mb ? __fmul_rn((float)cntk, 0.25f) : 0.0f;
    alpha *= (1.0f - pm);  // exact
    const int i = mb ? cntk : 0;
    const float lg = (i == 0) ? lg0 : (i == 1) ? lg1 : (i == 2) ? lg2
                   : (i == 3) ? lg3 : 0.0f;
    zm[k] = __fadd_rn(lg, __fdiv_rn(__fsub_rn(zinv[k], zmax), 0.1f));
    zmS[tid][k] = zm[k];
  }
  zm[8] = __fdiv_rn(__fsub_rn(1e-10f, zmax), 0.1f);
  zmS[tid][8] = zm[8];
  // zinv, msk, cntP dead here; live: zm[9], alpha.

  // ---- phase 3: random_argmax (approx scan + margin-at-end fallback) ----
  uint32_t amPack = 0;
  uint32_t cA = (uint32_t)P * 9u;
  #pragma unroll 1
  for (int s = 0; s < 4; ++s) {
    int am = 0;
    float best = -3.4e38f, second = -3.4e38f;
    #pragma unroll
    for (int j = 0; j < 9; ++j) {
      uint32_t o0, o1;
      tf2x32(ka0, ka1, 0u, cA + (uint32_t)j, o0, o1);
      float vv = score_fast(o0 ^ o1, zm[j]);
      bool g = vv > best;
      second = g ? best : fmaxf(second, vv);
      best = g ? vv : best;
      am = g ? j : am;
    }
    bool fl = __fsub_rn(best, second) < BAND_A;
    if (__builtin_expect(__ballot(fl) != 0ull, 0)) {
      if (fl) {   // exec-masked exact redo of this sample, ROLLED (LDS zm)
        int ame = 0;
        float be = -3.4e38f;
        #pragma unroll 1
        for (int j = 0; j < 9; ++j) {
          uint32_t o0, o1;
          tf2x32(ka0, ka1, 0u, cA + (uint32_t)j, o0, o1);
          float nz = normal_exact(o0 ^ o1);
          float ve = __fadd_rn(zmS[tid][j], __fmul_rn(0.1f, nz));
          bool g = ve > be;
          be = g ? ve : be;
          ame = g ? j : ame;
        }
        am = ame;
      }
    }
    amPack += 1u << (3 * am);
    cA += STRIDE_A;
  }
  // zm dead here; live: amPack, alpha.

  // ---- phase 4: epilogue ----
  float rgb[3] = {0.0f, 0.0f, 0.0f};
  {
    const float4* c4 = reinterpret_cast<const float4*>(colors + (size_t)P * 24);
    float cc[24];
    #pragma unroll
    for (int q = 0; q < 6; ++q) {
      float4 t = c4[q];
      cc[q*4+0]=t.x; cc[q*4+1]=t.y; cc[q*4+2]=t.z; cc[q*4+3]=t.w;
    }
    #pragma unroll
    for (int c = 0; c < 3; ++c) {
      float acc = 0.0f;
      #pragma unroll
      for (int k = 0; k < 8; ++k) {
        float wk = __fmul_rn(0.25f, (float)((amPack >> (3 * k)) & 7u));
        acc = __fadd_rn(acc, __fmul_rn(wk, cc[k * 3 + c]));
      }
      float wb = __fmul_rn(0.25f, (float)((amPack >> 24) & 7u));
      rgb[c] = __fadd_rn(acc, __fmul_rn(wb, bg[c]));
    }
  }

  float4 o;
  o.x = rgb[0]; o.y = rgb[1]; o.z = rgb[2];
  o.w = __fsub_rn(1.0f, alpha);
  reinterpret_cast<float4*>(out)[P] = o;
}

extern "C" void kernel_launch(void* const* d_in, const int* in_sizes, int n_in,
                              void* d_out, int out_size, void* d_ws, size_t ws_size,
                              hipStream_t stream) {
  const float* colors = (const float*)d_in[0];
  const float* dists  = (const float*)d_in[1];
  const float* zbuf   = (const float*)d_in[2];
  const int*   p2f    = (const int*)d_in[3];
  const float* bg     = (const float*)d_in[4];
  float* out = (float*)d_out;
  dim3 grid(NPIX / 256), block(256);
  hipLaunchKernelGGL(RandomPhongShader_kernel, grid, block, 0, stream,
                     colors, dists, zbuf, p2f, bg, out);
}